// Round 1
// baseline (1654.441 us; speedup 1.0000x reference)
//
#include <hip/hip_runtime.h>
#include <hip/hip_bf16.h>
#include <cstdint>
#include <cstddef>

// Problem: out[M,N] = x[M,K] @ W[N,K]^T + bias[N], W = (q - zp)*scale
// M = B*S = 8192, K = 4096, N = 11008. fp32 in/out, q int32.
#define M_DIM 8192
#define N_DIM 11008
#define K_DIM 4096

constexpr int BM = 128, BN = 128, BK = 64;

typedef __bf16 bf16x8 __attribute__((ext_vector_type(8)));
typedef float  f32x4  __attribute__((ext_vector_type(4)));

__device__ inline __bf16 to_bf16(float f) {
    __hip_bfloat16 h = __float2bfloat16(f);
    return *reinterpret_cast<__bf16*>(&h);
}

union Pack4 { __bf16 h[4]; uint2 u; };

// ---------------- conversion kernels (bf16 fast path) ----------------

__global__ void cvt_x_kernel(const float* __restrict__ x, __bf16* __restrict__ out) {
    int i = blockIdx.x * blockDim.x + threadIdx.x;   // one float4 per thread
    float4 v = *reinterpret_cast<const float4*>(x + (size_t)i * 4);
    Pack4 p;
    p.h[0] = to_bf16(v.x); p.h[1] = to_bf16(v.y);
    p.h[2] = to_bf16(v.z); p.h[3] = to_bf16(v.w);
    *reinterpret_cast<uint2*>(out + (size_t)i * 4) = p.u;
}

__global__ void cvt_w_kernel(const int* __restrict__ q,
                             const float* __restrict__ scale_p,
                             const float* __restrict__ zp_p,
                             __bf16* __restrict__ out) {
    const float scale = *scale_p;
    const float nzs   = -(*zp_p) * scale;   // (q - zp)*s = q*s + (-zp*s)
    int i = blockIdx.x * blockDim.x + threadIdx.x;
    int4 v = *reinterpret_cast<const int4*>(q + (size_t)i * 4);
    Pack4 p;
    p.h[0] = to_bf16((float)v.x * scale + nzs);
    p.h[1] = to_bf16((float)v.y * scale + nzs);
    p.h[2] = to_bf16((float)v.z * scale + nzs);
    p.h[3] = to_bf16((float)v.w * scale + nzs);
    *reinterpret_cast<uint2*>(out + (size_t)i * 4) = p.u;
}

// ---------------- shared GEMM pieces ----------------

__device__ inline void mma_tile(const __bf16* As, const __bf16* Bs,
                                f32x4 acc[4][4], int lane, int wm, int wn) {
    const int mrow = lane & 15;
#pragma unroll
    for (int ks = 0; ks < 2; ++ks) {
        const int kq = ks * 32 + (lane >> 4) * 8;
        bf16x8 a[4], b[4];
#pragma unroll
        for (int i = 0; i < 4; ++i) {
            a[i] = *reinterpret_cast<const bf16x8*>(As + (wm + i * 16 + mrow) * BK + kq);
            b[i] = *reinterpret_cast<const bf16x8*>(Bs + (wn + i * 16 + mrow) * BK + kq);
        }
#pragma unroll
        for (int i = 0; i < 4; ++i)
#pragma unroll
            for (int j = 0; j < 4; ++j)
                acc[i][j] = __builtin_amdgcn_mfma_f32_16x16x32_bf16(a[i], b[j], acc[i][j], 0, 0, 0);
    }
}

__device__ inline void epilogue(f32x4 acc[4][4], const float* __restrict__ bias,
                                float* __restrict__ C,
                                int bm, int bn, int wm, int wn, int lane) {
    const int col = lane & 15;
    const int rq  = (lane >> 4) * 4;
#pragma unroll
    for (int j = 0; j < 4; ++j) {
        const int n  = bn + wn + j * 16 + col;
        const float bj = bias[n];
#pragma unroll
        for (int i = 0; i < 4; ++i) {
            size_t base = (size_t)(bm + wm + i * 16 + rq) * N_DIM + n;
#pragma unroll
            for (int r = 0; r < 4; ++r)
                C[base + (size_t)r * N_DIM] = acc[i][j][r] + bj;
        }
    }
}

__device__ inline void async_load16(const void* gsrc, void* ldst) {
    __builtin_amdgcn_global_load_lds(
        (const __attribute__((address_space(1))) unsigned int*)gsrc,
        (__attribute__((address_space(3))) unsigned int*)ldst, 16, 0, 0);
}

// ---------------- fast path: bf16 GEMM with global_load_lds staging ----------------

__global__ __launch_bounds__(256)
void gemm_bf16_kernel(const __bf16* __restrict__ A, const __bf16* __restrict__ B,
                      const float* __restrict__ bias, float* __restrict__ C) {
    __shared__ __align__(16) __bf16 As[BM * BK];
    __shared__ __align__(16) __bf16 Bs[BN * BK];

    const int tid  = threadIdx.x;
    const int lane = tid & 63;
    const int wave = tid >> 6;
    const int bm = blockIdx.y * BM;
    const int bn = blockIdx.x * BN;
    const int wm = (wave >> 1) * 64;
    const int wn = (wave & 1) * 64;

    f32x4 acc[4][4] = {};

    // staging: 16 chunks of 1KB each (8 rows x 64 bf16); wave w owns chunks 4w..4w+3
    const int r_in_chunk = lane >> 3;        // 0..7
    const int c8         = (lane & 7) * 8;   // k offset, 8 bf16 = 16B

    for (int k0 = 0; k0 < K_DIM; k0 += BK) {
        __syncthreads();   // previous tile fully consumed
#pragma unroll
        for (int j = 0; j < 4; ++j) {
            const int c   = wave * 4 + j;
            const int row = c * 8 + r_in_chunk;
            async_load16(A + (size_t)(bm + row) * K_DIM + k0 + c8,
                         (char*)As + c * 1024 + lane * 16);
            async_load16(B + (size_t)(bn + row) * K_DIM + k0 + c8,
                         (char*)Bs + c * 1024 + lane * 16);
        }
        __syncthreads();   // drains vmcnt (global_load_lds) per m97 behavior
        mma_tile(As, Bs, acc, lane, wm, wn);
    }

    epilogue(acc, bias, C, bm, bn, wm, wn, lane);
}

// ---------------- fallback: fused dequant GEMM (no workspace needed) ----------------

__global__ __launch_bounds__(256)
void gemm_fused_kernel(const float* __restrict__ A, const int* __restrict__ Q,
                       const float* __restrict__ scale_p, const float* __restrict__ zp_p,
                       const float* __restrict__ bias, float* __restrict__ C) {
    __shared__ __align__(16) __bf16 As[BM * BK];
    __shared__ __align__(16) __bf16 Bs[BN * BK];

    const float scale = *scale_p;
    const float nzs   = -(*zp_p) * scale;

    const int tid  = threadIdx.x;
    const int lane = tid & 63;
    const int wave = tid >> 6;
    const int bm = blockIdx.y * BM;
    const int bn = blockIdx.x * BN;
    const int wm = (wave >> 1) * 64;
    const int wn = (wave & 1) * 64;

    f32x4 acc[4][4] = {};

    for (int k0 = 0; k0 < K_DIM; k0 += BK) {
        __syncthreads();
#pragma unroll
        for (int j = 0; j < 8; ++j) {
            const int e   = j * 1024 + tid * 4;   // element index in 128x64 tile
            const int row = e >> 6;
            const int col = e & 63;
            float4 v = *reinterpret_cast<const float4*>(A + (size_t)(bm + row) * K_DIM + k0 + col);
            Pack4 p;
            p.h[0] = to_bf16(v.x); p.h[1] = to_bf16(v.y);
            p.h[2] = to_bf16(v.z); p.h[3] = to_bf16(v.w);
            *reinterpret_cast<uint2*>(As + e) = p.u;

            int4 qv = *reinterpret_cast<const int4*>(Q + (size_t)(bn + row) * K_DIM + k0 + col);
            Pack4 pq;
            pq.h[0] = to_bf16((float)qv.x * scale + nzs);
            pq.h[1] = to_bf16((float)qv.y * scale + nzs);
            pq.h[2] = to_bf16((float)qv.z * scale + nzs);
            pq.h[3] = to_bf16((float)qv.w * scale + nzs);
            *reinterpret_cast<uint2*>(Bs + e) = pq.u;
        }
        __syncthreads();
        mma_tile(As, Bs, acc, lane, wm, wn);
    }

    epilogue(acc, bias, C, bm, bn, wm, wn, lane);
}

// ---------------- launch ----------------

extern "C" void kernel_launch(void* const* d_in, const int* in_sizes, int n_in,
                              void* d_out, int out_size, void* d_ws, size_t ws_size,
                              hipStream_t stream) {
    const float* x     = (const float*)d_in[0];
    const int*   qw    = (const int*)d_in[1];
    const float* scale = (const float*)d_in[2];
    const float* zp    = (const float*)d_in[3];
    const float* bias  = (const float*)d_in[4];
    float* out = (float*)d_out;

    const size_t needA = (size_t)M_DIM * K_DIM * sizeof(__bf16);   // 67.1 MB
    const size_t needB = (size_t)N_DIM * K_DIM * sizeof(__bf16);   // 90.2 MB
    dim3 grid(N_DIM / BN, M_DIM / BM);   // 86 x 64

    if (ws_size >= needA + needB) {
        __bf16* Abf = (__bf16*)d_ws;
        __bf16* Bbf = (__bf16*)((char*)d_ws + needA);
        cvt_x_kernel<<<(M_DIM * (size_t)K_DIM / 4) / 256, 256, 0, stream>>>(x, Abf);
        cvt_w_kernel<<<(N_DIM * (size_t)K_DIM / 4) / 256, 256, 0, stream>>>(qw, scale, zp, Bbf);
        gemm_bf16_kernel<<<grid, 256, 0, stream>>>(Abf, Bbf, bias, out);
    } else {
        gemm_fused_kernel<<<grid, 256, 0, stream>>>(x, qw, scale, zp, bias, out);
    }
}